// Round 3
// baseline (6146.671 us; speedup 1.0000x reference)
//
#include <hip/hip_runtime.h>

typedef __attribute__((ext_vector_type(4))) float f32x4;
typedef __attribute__((ext_vector_type(8))) __bf16 bf16x8;

#define SEQ   257
#define NBATCH 32
#define DIMD  512
#define FFD   2048
#define NLYR  8
#define MROWS (NBATCH*SEQ)   /* 8224 */
#define MPAD  8320           /* 65*128 */
#define MSTEM 8192
#define KSTEM 4096
#define QKVD  1536

__device__ __forceinline__ unsigned short f2bf(float f) {
  unsigned int u = __float_as_uint(f);
  return (unsigned short)((u + 0x7FFFu + ((u >> 16) & 1u)) >> 16);
}
__device__ __forceinline__ float elu1(float x) { return x > 0.f ? x + 1.f : expf(x); }

__device__ __forceinline__ void gload16(const void* g, void* l) {
  __builtin_amdgcn_global_load_lds((__attribute__((address_space(1))) void*)g,
                                   (__attribute__((address_space(3))) void*)l, 16, 0, 0);
}

// ---------------------------------------------------------------- GEMM
// C[M,N] = A[M,K](bf16) * BT[N,K](bf16) + bias.
// CFG 0: BM=128,BN=128 (waves 2x2, 4x4 frags). CFG 1: BM=128,BN=64 (waves 4x1, 2x4 frags).
// EPI 0: fp32 out. EPI 1: gelu -> bf16 out.
// LDS tiles XOR-swizzled: 16B slot s of row r holds global slot s^(r&7).
template<int CFG, int EPI>
__global__ __launch_bounds__(256)
void gemm_bt(const unsigned short* __restrict__ A,
             const unsigned short* __restrict__ BT,
             const float* __restrict__ bias,
             void* __restrict__ Cout, int K, int Nn) {
  constexpr int WR = CFG ? 4 : 2;
  constexpr int WC = CFG ? 1 : 2;
  constexpr int MW = CFG ? 2 : 4;
  constexpr int NW = 4;
  constexpr int BM = WR * MW * 16;   // 128
  constexpr int BN = WC * NW * 16;   // 128 or 64
  __shared__ __align__(16) unsigned short sA[BM * 64];
  __shared__ __align__(16) unsigned short sB[BN * 64];
  const int tid = threadIdx.x;
  const int w = tid >> 6, l = tid & 63;
  const int wr = CFG ? w : (w >> 1);
  const int wc = CFG ? 0 : (w & 1);
  const long tm = (long)blockIdx.x * BM;
  const long tn = (long)blockIdx.y * BN;
  const int lr = l & 15, lg = l >> 4;
  const int lr7 = lr & 7;

  f32x4 acc[MW][NW];
#pragma unroll
  for (int m = 0; m < MW; ++m)
#pragma unroll
    for (int n = 0; n < NW; ++n) acc[m][n] = (f32x4){0.f, 0.f, 0.f, 0.f};

  for (int k0 = 0; k0 < K; k0 += 64) {
#pragma unroll
    for (int j = 0; j < BM * 8 / 256; ++j) {
      const int ch = j * 256 + tid;
      const int r = ch >> 3, s = ch & 7;
      gload16(A + (tm + r) * (long)K + k0 + ((s ^ (r & 7)) * 8), sA + ch * 8);
    }
#pragma unroll
    for (int j = 0; j < BN * 8 / 256; ++j) {
      const int ch = j * 256 + tid;
      const int r = ch >> 3, s = ch & 7;
      gload16(BT + (tn + r) * (long)K + k0 + ((s ^ (r & 7)) * 8), sB + ch * 8);
    }
    __syncthreads();
#pragma unroll
    for (int kk = 0; kk < 2; ++kk) {
      const int sl = ((lg + kk * 4) ^ lr7) * 8;
      bf16x8 af[MW], bfr[NW];
#pragma unroll
      for (int m = 0; m < MW; ++m)
        af[m] = *(const bf16x8*)(sA + (wr * MW * 16 + m * 16 + lr) * 64 + sl);
#pragma unroll
      for (int n = 0; n < NW; ++n)
        bfr[n] = *(const bf16x8*)(sB + (wc * NW * 16 + n * 16 + lr) * 64 + sl);
#pragma unroll
      for (int m = 0; m < MW; ++m)
#pragma unroll
        for (int n = 0; n < NW; ++n)
          acc[m][n] = __builtin_amdgcn_mfma_f32_16x16x32_bf16(af[m], bfr[n], acc[m][n], 0, 0, 0);
    }
    __syncthreads();
  }
#pragma unroll
  for (int m = 0; m < MW; ++m) {
    const long gr0 = tm + wr * MW * 16 + m * 16 + lg * 4;
#pragma unroll
    for (int n = 0; n < NW; ++n) {
      const long gc = tn + wc * NW * 16 + n * 16 + lr;
      const float bv = bias ? bias[gc] : 0.f;
#pragma unroll
      for (int j = 0; j < 4; ++j) {
        float v = acc[m][n][j] + bv;
        if (EPI == 0) {
          ((float*)Cout)[(gr0 + j) * (long)Nn + gc] = v;
        } else {
          float g = 0.5f * v * (1.f + erff(v * 0.70710678118f));
          ((unsigned short*)Cout)[(gr0 + j) * (long)Nn + gc] = f2bf(g);
        }
      }
    }
  }
}

// ------------------------------------------------- batched transpose (fp32 -> bf16/fp32)
// src: (L, K, N) fp32 at stride K*N per z; dst rows n at dst + z*dstZ + n*K + k.
template<int OUT_BF>
__global__ void transpose_k(const float* __restrict__ src, void* __restrict__ dst,
                            int K, int N, long dstZ) {
  __shared__ float t[32][33];
  const long lz = blockIdx.z;
  const float* S = src + lz * (long)K * N;
  const long k0 = (long)blockIdx.x * 32, n0 = (long)blockIdx.y * 32;
  for (int i = threadIdx.y; i < 32; i += 8)
    t[i][threadIdx.x] = S[(k0 + i) * (long)N + n0 + threadIdx.x];
  __syncthreads();
  for (int i = threadIdx.y; i < 32; i += 8) {
    long o = lz * dstZ + (n0 + i) * (long)K + k0 + threadIdx.x;
    float val = t[threadIdx.x][i];
    if (OUT_BF) ((unsigned short*)dst)[o] = f2bf(val);
    else ((float*)dst)[o] = val;
  }
}

// ------------------------------------------------- W_eff: WeT[o, p*256+c] + fused stem bias
__global__ __launch_bounds__(256)
void weff_kernel(const float* __restrict__ embWT, const float* __restrict__ convW,
                 const float* __restrict__ emb_b, const float* __restrict__ conv_b,
                 unsigned short* __restrict__ WeT, float* __restrict__ bias2) {
  __shared__ float sc[8192];
  const int o = blockIdx.x;
  const float* C = convW + (long)o * 8192;
  for (int i = threadIdx.x; i < 8192; i += 256) sc[i] = C[i];
  __syncthreads();
  const int c = threadIdx.x;
  float acc[16];
#pragma unroll
  for (int p = 0; p < 16; ++p) acc[p] = 0.f;
  for (int d = 0; d < 512; ++d) {
    float ev = embWT[d * 256 + c];
#pragma unroll
    for (int p = 0; p < 16; ++p) acc[p] += ev * sc[d * 16 + p];
  }
#pragma unroll
  for (int p = 0; p < 16; ++p) WeT[(long)o * 4096 + p * 256 + c] = f2bf(acc[p]);
  float lb = 0.f;
  for (int d = c; d < 512; d += 256) {
    float s16 = 0.f;
#pragma unroll
    for (int p = 0; p < 16; ++p) s16 += sc[d * 16 + p];
    lb += emb_b[d] * s16;
  }
#pragma unroll
  for (int of = 1; of < 64; of <<= 1) lb += __shfl_xor(lb, of, 64);
  __shared__ float red[4];
  if ((threadIdx.x & 63) == 0) red[threadIdx.x >> 6] = lb;
  __syncthreads();
  if (threadIdx.x == 0) bias2[o] = red[0] + red[1] + red[2] + red[3] + conv_b[o];
}

// ------------------------------------------------- misc small kernels
__global__ void f32_to_bf16_k(const float* __restrict__ in, unsigned short* __restrict__ out, long n4) {
  long i = (long)blockIdx.x * blockDim.x + threadIdx.x;
  const long stride = (long)gridDim.x * blockDim.x;
  for (; i < n4; i += stride) {
    float4 v = ((const float4*)in)[i];
    ushort4 o; o.x = f2bf(v.x); o.y = f2bf(v.y); o.z = f2bf(v.z); o.w = f2bf(v.w);
    ((ushort4*)out)[i] = o;
  }
}

__global__ void rotary_k(float* __restrict__ cosT, float* __restrict__ sinT) {
  int idx = blockIdx.x * 256 + threadIdx.x;
  if (idx >= SEQ * 32) return;
  int s = idx >> 5, j = idx & 31;
  float inv = expf(-(float)(2 * j) * (1.f / 64.f) * 9.210340371976184f);
  float a = (float)s * inv;
  cosT[idx] = cosf(a);
  sinT[idx] = sinf(a);
}

__global__ void concat_bias_k(const float* __restrict__ bq, const float* __restrict__ bk,
                              const float* __restrict__ bv, float* __restrict__ bqkv) {
  int idx = blockIdx.x * 256 + threadIdx.x;
  if (idx >= NLYR * QKVD) return;
  int i = idx / QKVD, j = idx % QKVD;
  float v;
  if (j < 512) v = bq[i * 512 + j];
  else if (j < 1024) v = bk[i * 512 + j - 512];
  else v = bv[i * 512 + j - 1024];
  bqkv[idx] = v;
}

__global__ __launch_bounds__(256)
void masklen_k(const float* __restrict__ mask, float* __restrict__ mlen) {
  int n = blockIdx.x;
  float s = 0.f;
  for (int i = threadIdx.x; i < 4096; i += 256) s += mask[(long)n * 4096 + i];
#pragma unroll
  for (int of = 1; of < 64; of <<= 1) s += __shfl_xor(s, of, 64);
  __shared__ float red[4];
  if ((threadIdx.x & 63) == 0) red[threadIdx.x >> 6] = s;
  __syncthreads();
  if (threadIdx.x == 0) mlen[n] = ceilf((1.f + red[0] + red[1] + red[2] + red[3]) * (1.f / 16.f));
}

__global__ void assemble_x(const float* __restrict__ stem, const float* __restrict__ bias2,
                           const float* __restrict__ posemb, const float* __restrict__ cls,
                           float* __restrict__ Xf, unsigned short* __restrict__ Xbf) {
  long idx = (long)blockIdx.x * 256 + threadIdx.x;
  if (idx >= (long)MROWS * 128) return;
  long row = idx >> 7;
  int c4 = (int)(idx & 127) * 4;
  int n = (int)(row / SEQ), s = (int)(row % SEQ);
  float4 p = *(const float4*)(posemb + (long)s * DIMD + c4);
  float4 v;
  if (s == 0) {
    float4 cv = *(const float4*)(cls + c4);
    v.x = cv.x + p.x; v.y = cv.y + p.y; v.z = cv.z + p.z; v.w = cv.w + p.w;
  } else {
    float4 st = *(const float4*)(stem + ((long)(n * 256 + s - 1)) * DIMD + c4);
    float4 b2 = *(const float4*)(bias2 + c4);
    v.x = st.x + b2.x + p.x; v.y = st.y + b2.y + p.y; v.z = st.z + b2.z + p.z; v.w = st.w + b2.w + p.w;
  }
  *(float4*)(Xf + row * DIMD + c4) = v;
  ushort4 o; o.x = f2bf(v.x); o.y = f2bf(v.y); o.z = f2bf(v.z); o.w = f2bf(v.w);
  *(ushort4*)(Xbf + row * DIMD + c4) = o;
}

// rotary + elu(+1) on fused qkv buffer (q at +0, k at +512), in place. grid MROWS, block 256.
__global__ __launch_bounds__(256)
void rot_elu_k(float* __restrict__ QKV,
               const float* __restrict__ cosT, const float* __restrict__ sinT,
               const float* __restrict__ mlen) {
  int row = blockIdx.x;
  int n = row / SEQ, s = row % SEQ;
  int t = threadIdx.x, h = t >> 5, j = t & 31;
  long base = (long)row * QKVD + h * 64 + j;
  float c = cosT[s * 32 + j], si = sinT[s * 32 + j];
  float q0 = QKV[base], q1 = QKV[base + 32];
  QKV[base] = elu1(q0 * c - q1 * si);
  QKV[base + 32] = elu1(q1 * c + q0 * si);
  float km = ((float)s < mlen[n]) ? 1.f : 0.f;
  float k0 = QKV[base + 512], k1 = QKV[base + 544];
  QKV[base + 512] = elu1(k0 * c - k1 * si) * km;
  QKV[base + 544] = elu1(k1 * c + k0 * si) * km;
}

// KV[n,h,d,m] = sum_s K[n,s,h,d]*V[n,s,h,m]; Ksum[n,h,d]. grid 256 (n*8+h), block 512.
__global__ __launch_bounds__(512)
void kv_kernel(const float* __restrict__ QKV, float* __restrict__ KV, float* __restrict__ Ksum) {
  int n = blockIdx.x >> 3, h = blockIdx.x & 7;
  __shared__ float sK[64][64];
  __shared__ float sV[64][64];
  int t = threadIdx.x;
  int d = t & 63, mg = t >> 6;   // mg in 0..7
  float acc[8];
#pragma unroll
  for (int i = 0; i < 8; ++i) acc[i] = 0.f;
  float ks = 0.f;
  for (int s0 = 0; s0 < 320; s0 += 64) {
#pragma unroll
    for (int kk = 0; kk < 2; ++kk) {
      int idx = kk * 512 + t;
      int r = idx >> 4, c4 = (idx & 15) * 4;
      int srow = s0 + r;
      float4 kv = {0, 0, 0, 0}, vv = {0, 0, 0, 0};
      if (srow < SEQ) {
        long goff = ((long)(n * SEQ + srow)) * QKVD + h * 64 + c4;
        kv = *(const float4*)(QKV + goff + 512);
        vv = *(const float4*)(QKV + goff + 1024);
      }
      *(float4*)&sK[r][c4] = kv;
      *(float4*)&sV[r][c4] = vv;
    }
    __syncthreads();
    for (int s = 0; s < 64; ++s) {
      float kd = sK[s][d];
      if (mg == 0) ks += kd;
      float4 v0 = *(const float4*)&sV[s][mg * 8];
      float4 v1 = *(const float4*)&sV[s][mg * 8 + 4];
      acc[0] += kd * v0.x; acc[1] += kd * v0.y; acc[2] += kd * v0.z; acc[3] += kd * v0.w;
      acc[4] += kd * v1.x; acc[5] += kd * v1.y; acc[6] += kd * v1.z; acc[7] += kd * v1.w;
    }
    __syncthreads();
  }
  float* out = KV + ((long)(n * 8 + h)) * 4096 + d * 64 + mg * 8;
#pragma unroll
  for (int i = 0; i < 8; ++i) out[i] = acc[i];
  if (mg == 0) Ksum[(n * 8 + h) * 64 + d] = ks;
}

// attention out (bf16). grid (32, 65), block 512: thread=(h,m); 4 query rows per block.
__global__ __launch_bounds__(512)
void attn_out_k(const float* __restrict__ QKV, const float* __restrict__ KV,
                const float* __restrict__ Ksum, unsigned short* __restrict__ Obf) {
  int n = blockIdx.x, lg = blockIdx.y;
  int t = threadIdx.x, h = t >> 6, m = t & 63;
  __shared__ float sQ[4][512];
#pragma unroll
  for (int r = 0; r < 4; ++r) {
    int lq = lg * 4 + r;
    sQ[r][t] = (lq < SEQ) ? QKV[((long)(n * SEQ + lq)) * QKVD + t] : 0.f;
  }
  __syncthreads();
  float ksd = Ksum[(n * 8 + h) * 64 + m];
  float Zv[4];
#pragma unroll
  for (int r = 0; r < 4; ++r) {
    float z = sQ[r][h * 64 + m] * ksd;
#pragma unroll
    for (int of = 1; of < 64; of <<= 1) z += __shfl_xor(z, of, 64);
    Zv[r] = 1.f / (z + 1e-6f);
  }
  const float* kvp = KV + ((long)(n * 8 + h)) * 4096 + m;
  float acc[4] = {0.f, 0.f, 0.f, 0.f};
  for (int d = 0; d < 64; ++d) {
    float kvv = kvp[d * 64];
#pragma unroll
    for (int r = 0; r < 4; ++r) acc[r] += sQ[r][h * 64 + d] * kvv;
  }
#pragma unroll
  for (int r = 0; r < 4; ++r) {
    int lq = lg * 4 + r;
    if (lq < SEQ) Obf[((long)(n * SEQ + lq)) * DIMD + t] = f2bf(acc[r] * Zv[r]);
  }
}

// y = LN(x + a) -> fp32 + bf16. grid MROWS, block 128.
__global__ __launch_bounds__(128)
void add_ln_k(const float* __restrict__ X, const float* __restrict__ A,
              const float* __restrict__ g, const float* __restrict__ b,
              float* __restrict__ Yf, unsigned short* __restrict__ Ybf) {
  int row = blockIdx.x, t = threadIdx.x;
  long base = (long)row * DIMD + t * 4;
  float4 xv = *(const float4*)(X + base);
  float4 av = *(const float4*)(A + base);
  float4 s;
  s.x = xv.x + av.x; s.y = xv.y + av.y; s.z = xv.z + av.z; s.w = xv.w + av.w;
  float sum = s.x + s.y + s.z + s.w;
  float sq = s.x * s.x + s.y * s.y + s.z * s.z + s.w * s.w;
#pragma unroll
  for (int of = 1; of < 64; of <<= 1) { sum += __shfl_xor(sum, of, 64); sq += __shfl_xor(sq, of, 64); }
  __shared__ float red[4];
  if ((t & 63) == 0) { red[(t >> 6) * 2] = sum; red[(t >> 6) * 2 + 1] = sq; }
  __syncthreads();
  sum = red[0] + red[2]; sq = red[1] + red[3];
  float mean = sum * (1.f / 512.f);
  float var = sq * (1.f / 512.f) - mean * mean;
  float rstd = rsqrtf(var + 1e-5f);
  float4 gv = *(const float4*)(g + t * 4);
  float4 bv = *(const float4*)(b + t * 4);
  float4 y;
  y.x = (s.x - mean) * rstd * gv.x + bv.x;
  y.y = (s.y - mean) * rstd * gv.y + bv.y;
  y.z = (s.z - mean) * rstd * gv.z + bv.z;
  y.w = (s.w - mean) * rstd * gv.w + bv.w;
  *(float4*)(Yf + base) = y;
  ushort4 o; o.x = f2bf(y.x); o.y = f2bf(y.y); o.z = f2bf(y.z); o.w = f2bf(y.w);
  *(ushort4*)(Ybf + base) = o;
}

// final LN + output heads. grid MROWS, block 128. out fp32: [32 global][8192 local]
__global__ __launch_bounds__(128)
void final_head_k(const float* __restrict__ X, const float* __restrict__ g, const float* __restrict__ b,
                  const float* __restrict__ condemb, const int* __restrict__ cond,
                  const float* __restrict__ outgW, const float* __restrict__ outgb,
                  const float* __restrict__ outlW, const float* __restrict__ outlb,
                  float* __restrict__ out) {
  int row = blockIdx.x, t = threadIdx.x;
  int n = row / SEQ, s = row % SEQ;
  long base = (long)row * DIMD + t * 4;
  float4 xv = *(const float4*)(X + base);
  float sum = xv.x + xv.y + xv.z + xv.w;
  float sq = xv.x * xv.x + xv.y * xv.y + xv.z * xv.z + xv.w * xv.w;
#pragma unroll
  for (int of = 1; of < 64; of <<= 1) { sum += __shfl_xor(sum, of, 64); sq += __shfl_xor(sq, of, 64); }
  __shared__ float red[4];
  if ((t & 63) == 0) { red[(t >> 6) * 2] = sum; red[(t >> 6) * 2 + 1] = sq; }
  __syncthreads();
  sum = red[0] + red[2]; sq = red[1] + red[3];
  float mean = sum * (1.f / 512.f);
  float var = sq * (1.f / 512.f) - mean * mean;
  float rstd = rsqrtf(var + 1e-5f);
  float4 gv = *(const float4*)(g + t * 4);
  float4 bv = *(const float4*)(b + t * 4);
  const float* wsel = (s == 0) ? outgW : outlW;
  const float* ce = condemb + (long)cond[n] * DIMD;
  float4 wv = *(const float4*)(wsel + t * 4);
  float4 cv = *(const float4*)(ce + t * 4);
  float l0 = (xv.x - mean) * rstd * gv.x + bv.x;
  float l1 = (xv.y - mean) * rstd * gv.y + bv.y;
  float l2 = (xv.z - mean) * rstd * gv.z + bv.z;
  float l3 = (xv.w - mean) * rstd * gv.w + bv.w;
  float pl = l0 * wv.x + l1 * wv.y + l2 * wv.z + l3 * wv.w;
  float pc = l0 * cv.x + l1 * cv.y + l2 * cv.z + l3 * cv.w;
#pragma unroll
  for (int of = 1; of < 64; of <<= 1) { pl += __shfl_xor(pl, of, 64); pc += __shfl_xor(pc, of, 64); }
  __shared__ float red2[4];
  if ((t & 63) == 0) { red2[(t >> 6) * 2] = pl; red2[(t >> 6) * 2 + 1] = pc; }
  __syncthreads();
  if (t == 0) {
    float res = red2[0] + red2[2] + red2[1] + red2[3] + ((s == 0) ? outgb[0] : outlb[0]);
    long oi = (s == 0) ? (long)n : (32 + (long)n * 256 + (s - 1));
    out[oi] = res;
  }
}

// ---------------------------------------------------------------- host
extern "C" void kernel_launch(void* const* d_in, const int* in_sizes, int n_in,
                              void* d_out, int out_size, void* d_ws, size_t ws_size,
                              hipStream_t stream) {
  const float* inputs    = (const float*)d_in[0];
  const float* input_mask= (const float*)d_in[1];
  const int*   cond      = (const int*)d_in[2];
  const float* emb_W     = (const float*)d_in[3];
  const float* emb_b     = (const float*)d_in[4];
  const float* conv_W    = (const float*)d_in[5];
  const float* conv_b    = (const float*)d_in[6];
  const float* pos_emb   = (const float*)d_in[7];
  const float* cls_token = (const float*)d_in[8];
  const float* Wq = (const float*)d_in[9];   const float* bq = (const float*)d_in[10];
  const float* Wk = (const float*)d_in[11];  const float* bk = (const float*)d_in[12];
  const float* Wv = (const float*)d_in[13];  const float* bv = (const float*)d_in[14];
  const float* Wo = (const float*)d_in[15];  const float* bo = (const float*)d_in[16];
  const float* ln1_g = (const float*)d_in[17]; const float* ln1_b = (const float*)d_in[18];
  const float* W1 = (const float*)d_in[19];  const float* b1 = (const float*)d_in[20];
  const float* W2 = (const float*)d_in[21];  const float* b2 = (const float*)d_in[22];
  const float* ln2_g = (const float*)d_in[23]; const float* ln2_b = (const float*)d_in[24];
  const float* normf_g = (const float*)d_in[25]; const float* normf_b = (const float*)d_in[26];
  const float* cond_emb = (const float*)d_in[27];
  const float* outg_W = (const float*)d_in[28]; const float* outg_b = (const float*)d_in[29];
  const float* outl_W = (const float*)d_in[30]; const float* outl_b = (const float*)d_in[31];

  char* ws = (char*)d_ws;
  size_t off = 0;
  auto alloc = [&](size_t bytes) -> char* {
    char* p = ws + off;
    off += (bytes + 255) & ~(size_t)255;
    return p;
  };
  unsigned short* WeT   = (unsigned short*)alloc((size_t)512 * 4096 * 2);
  float*          embWT = (float*)alloc((size_t)512 * 256 * 4);
  float*          bias2 = (float*)alloc(512 * 4);
  float*          cosT  = (float*)alloc(SEQ * 32 * 4);
  float*          sinT  = (float*)alloc(SEQ * 32 * 4);
  float*          mlen  = (float*)alloc(32 * 4);
  unsigned short* Wqkv  = (unsigned short*)alloc((size_t)NLYR * QKVD * 512 * 2);
  float*          bqkv  = (float*)alloc((size_t)NLYR * QKVD * 4);
  unsigned short* WoT = (unsigned short*)alloc((size_t)NLYR * 512 * 512 * 2);
  unsigned short* W1T = (unsigned short*)alloc((size_t)NLYR * 2048 * 512 * 2);
  unsigned short* W2T = (unsigned short*)alloc((size_t)NLYR * 512 * 2048 * 2);
  // in_bf (64 MB) only needed before the stem GEMM; tqkv (51 MB) aliases it.
  char*           big  = alloc((size_t)MSTEM * KSTEM * 2);
  unsigned short* in_bf = (unsigned short*)big;
  float*          tqkv  = (float*)big;
  float*          x_f  = (float*)alloc((size_t)MPAD * DIMD * 4);
  unsigned short* x_bf = (unsigned short*)alloc((size_t)MPAD * DIMD * 2);
  float*          y_f  = (float*)alloc((size_t)MPAD * DIMD * 4);
  unsigned short* y_bf = (unsigned short*)alloc((size_t)MPAD * DIMD * 2);
  float*          t0   = (float*)alloc((size_t)MPAD * DIMD * 4);
  unsigned short* attn_bf = (unsigned short*)alloc((size_t)MPAD * DIMD * 2);
  unsigned short* h_bf = (unsigned short*)alloc((size_t)MPAD * FFD * 2);
  float*          KV   = (float*)alloc((size_t)32 * 8 * 64 * 64 * 4);
  float*          Ksum = (float*)alloc((size_t)32 * 8 * 64 * 4);
  (void)ws_size; (void)in_sizes; (void)n_in; (void)out_size;

  dim3 tb(32, 8);
  // fused QKV weight: per layer rows [0..512)=Wq^T, [512..1024)=Wk^T, [1024..1536)=Wv^T
  transpose_k<1><<<dim3(16, 16, 8), tb, 0, stream>>>(Wq, Wqkv, 512, 512, (long)QKVD * 512);
  transpose_k<1><<<dim3(16, 16, 8), tb, 0, stream>>>(Wk, Wqkv + (size_t)512 * 512, 512, 512, (long)QKVD * 512);
  transpose_k<1><<<dim3(16, 16, 8), tb, 0, stream>>>(Wv, Wqkv + (size_t)1024 * 512, 512, 512, (long)QKVD * 512);
  transpose_k<1><<<dim3(16, 16, 8), tb, 0, stream>>>(Wo, WoT, 512, 512, (long)512 * 512);
  transpose_k<1><<<dim3(16, 64, 8), tb, 0, stream>>>(W1, W1T, 512, 2048, (long)512 * 2048);
  transpose_k<1><<<dim3(64, 16, 8), tb, 0, stream>>>(W2, W2T, 2048, 512, (long)2048 * 512);
  transpose_k<0><<<dim3(8, 16, 1), tb, 0, stream>>>(emb_W, embWT, 256, 512, 0);
  concat_bias_k<<<(NLYR * QKVD + 255) / 256, 256, 0, stream>>>(bq, bk, bv, bqkv);
  weff_kernel<<<512, 256, 0, stream>>>(embWT, conv_W, emb_b, conv_b, WeT, bias2);
  f32_to_bf16_k<<<4096, 256, 0, stream>>>(inputs, in_bf, (long)MSTEM * KSTEM / 4);
  rotary_k<<<(SEQ * 32 + 255) / 256, 256, 0, stream>>>(cosT, sinT);
  masklen_k<<<32, 256, 0, stream>>>(input_mask, mlen);

  // stem GEMM: (8192 x 4096) @ (4096 x 512) -> t0   [CFG1: BN=64, grid 512]
  gemm_bt<1, 0><<<dim3(MSTEM / 128, 8), 256, 0, stream>>>(in_bf, WeT, nullptr, t0, KSTEM, DIMD);
  assemble_x<<<(MROWS * 128 + 255) / 256, 256, 0, stream>>>(t0, bias2, pos_emb, cls_token, x_f, x_bf);

  for (int i = 0; i < NLYR; ++i) {
    const unsigned short* wqkv = Wqkv + (size_t)i * QKVD * 512;
    const unsigned short* wo = WoT + (size_t)i * 512 * 512;
    const unsigned short* w1 = W1T + (size_t)i * 2048 * 512;
    const unsigned short* w2 = W2T + (size_t)i * 512 * 2048;
    // fused QKV: (8320 x 512) @ (512 x 1536) -> tqkv  [CFG0, grid 780]
    gemm_bt<0, 0><<<dim3(MPAD / 128, QKVD / 128), 256, 0, stream>>>(x_bf, wqkv, bqkv + i * QKVD, tqkv, 512, QKVD);
    rot_elu_k<<<MROWS, 256, 0, stream>>>(tqkv, cosT, sinT, mlen);
    kv_kernel<<<256, 512, 0, stream>>>(tqkv, KV, Ksum);
    attn_out_k<<<dim3(32, 65), 512, 0, stream>>>(tqkv, KV, Ksum, attn_bf);
    // O-proj [CFG1, grid 520]
    gemm_bt<1, 0><<<dim3(MPAD / 128, 8), 256, 0, stream>>>(attn_bf, wo, bo + i * 512, t0, 512, 512);
    add_ln_k<<<MROWS, 128, 0, stream>>>(x_f, t0, ln1_g + i * 512, ln1_b + i * 512, y_f, y_bf);
    // FF1 [CFG0, grid 1040]
    gemm_bt<0, 1><<<dim3(MPAD / 128, 16), 256, 0, stream>>>(y_bf, w1, b1 + i * 2048, h_bf, 512, 2048);
    // FF2 [CFG1, grid 520]
    gemm_bt<1, 0><<<dim3(MPAD / 128, 8), 256, 0, stream>>>(h_bf, w2, b2 + i * 512, t0, 2048, 512);
    add_ln_k<<<MROWS, 128, 0, stream>>>(y_f, t0, ln2_g + i * 512, ln2_b + i * 512, x_f, x_bf);
  }
  final_head_k<<<MROWS, 128, 0, stream>>>(x_f, normf_g, normf_b, cond_emb, cond,
                                          outg_W, outg_b, outl_W, outl_b, (float*)d_out);
}

// Round 4
// 1990.924 us; speedup vs baseline: 3.0873x; 3.0873x over previous
//
#include <hip/hip_runtime.h>

typedef __attribute__((ext_vector_type(4))) float f32x4;
typedef __attribute__((ext_vector_type(8))) __bf16 bf16x8;

#define SEQ   257
#define NBATCH 32
#define DIMD  512
#define FFD   2048
#define NLYR  8
#define MROWS (NBATCH*SEQ)   /* 8224 */
#define MPAD  8320           /* 65*128 */
#define MSTEM 8192
#define KSTEM 4096
#define QKVD  1536

__device__ __forceinline__ unsigned short f2bf(float f) {
  unsigned int u = __float_as_uint(f);
  return (unsigned short)((u + 0x7FFFu + ((u >> 16) & 1u)) >> 16);
}
__device__ __forceinline__ float elu1(float x) { return x > 0.f ? x + 1.f : expf(x); }

__device__ __forceinline__ void gload16(const void* g, void* l) {
  __builtin_amdgcn_global_load_lds((__attribute__((address_space(1))) void*)g,
                                   (__attribute__((address_space(3))) void*)l, 16, 0, 0);
}

// ---------------------------------------------------------------- GEMM
// C[M,N] = A[M,K](bf16) * BT[N,K](bf16) + bias.
// CFG 0: BM=128,BN=128 (waves 2x2, 4x4 frags). CFG 1: BM=128,BN=64 (waves 4x1, 2x4 frags).
// EPI 0: fp32 out. EPI 1: gelu -> bf16 out.
// LDS tiles XOR-swizzled: 16B slot s of row r holds global slot s^(r&7).
template<int CFG, int EPI>
__global__ __launch_bounds__(256)
void gemm_bt(const unsigned short* __restrict__ A,
             const unsigned short* __restrict__ BT,
             const float* __restrict__ bias,
             void* __restrict__ Cout, int K, int Nn) {
  constexpr int WR = CFG ? 4 : 2;
  constexpr int WC = CFG ? 1 : 2;
  constexpr int MW = CFG ? 2 : 4;
  constexpr int NW = 4;
  constexpr int BM = WR * MW * 16;   // 128
  constexpr int BN = WC * NW * 16;   // 128 or 64
  __shared__ __align__(16) unsigned short sA[BM * 64];
  __shared__ __align__(16) unsigned short sB[BN * 64];
  const int tid = threadIdx.x;
  const int w = tid >> 6, l = tid & 63;
  const int wr = CFG ? w : (w >> 1);
  const int wc = CFG ? 0 : (w & 1);
  const long tm = (long)blockIdx.x * BM;
  const long tn = (long)blockIdx.y * BN;
  const int lr = l & 15, lg = l >> 4;
  const int lr7 = lr & 7;

  f32x4 acc[MW][NW];
#pragma unroll
  for (int m = 0; m < MW; ++m)
#pragma unroll
    for (int n = 0; n < NW; ++n) acc[m][n] = (f32x4){0.f, 0.f, 0.f, 0.f};

  for (int k0 = 0; k0 < K; k0 += 64) {
#pragma unroll
    for (int j = 0; j < BM * 8 / 256; ++j) {
      const int ch = j * 256 + tid;
      const int r = ch >> 3, s = ch & 7;
      gload16(A + (tm + r) * (long)K + k0 + ((s ^ (r & 7)) * 8), sA + ch * 8);
    }
#pragma unroll
    for (int j = 0; j < BN * 8 / 256; ++j) {
      const int ch = j * 256 + tid;
      const int r = ch >> 3, s = ch & 7;
      gload16(BT + (tn + r) * (long)K + k0 + ((s ^ (r & 7)) * 8), sB + ch * 8);
    }
    __syncthreads();
#pragma unroll
    for (int kk = 0; kk < 2; ++kk) {
      const int sl = ((lg + kk * 4) ^ lr7) * 8;
      bf16x8 af[MW], bfr[NW];
#pragma unroll
      for (int m = 0; m < MW; ++m)
        af[m] = *(const bf16x8*)(sA + (wr * MW * 16 + m * 16 + lr) * 64 + sl);
#pragma unroll
      for (int n = 0; n < NW; ++n)
        bfr[n] = *(const bf16x8*)(sB + (wc * NW * 16 + n * 16 + lr) * 64 + sl);
#pragma unroll
      for (int m = 0; m < MW; ++m)
#pragma unroll
        for (int n = 0; n < NW; ++n)
          acc[m][n] = __builtin_amdgcn_mfma_f32_16x16x32_bf16(af[m], bfr[n], acc[m][n], 0, 0, 0);
    }
    __syncthreads();
  }
#pragma unroll
  for (int m = 0; m < MW; ++m) {
    const long gr0 = tm + wr * MW * 16 + m * 16 + lg * 4;
#pragma unroll
    for (int n = 0; n < NW; ++n) {
      const long gc = tn + wc * NW * 16 + n * 16 + lr;
      const float bv = bias ? bias[gc] : 0.f;
#pragma unroll
      for (int j = 0; j < 4; ++j) {
        float v = acc[m][n][j] + bv;
        if (EPI == 0) {
          ((float*)Cout)[(gr0 + j) * (long)Nn + gc] = v;
        } else {
          float g = 0.5f * v * (1.f + erff(v * 0.70710678118f));
          ((unsigned short*)Cout)[(gr0 + j) * (long)Nn + gc] = f2bf(g);
        }
      }
    }
  }
}

// ------------------------------------------------- batched transpose (fp32 -> bf16/fp32)
// src: (L, K, N) fp32 at stride K*N per z; dst rows n at dst + z*dstZ + n*K + k.
template<int OUT_BF>
__global__ void transpose_k(const float* __restrict__ src, void* __restrict__ dst,
                            int K, int N, long dstZ) {
  __shared__ float t[32][33];
  const long lz = blockIdx.z;
  const float* S = src + lz * (long)K * N;
  const long k0 = (long)blockIdx.x * 32, n0 = (long)blockIdx.y * 32;
  for (int i = threadIdx.y; i < 32; i += 8)
    t[i][threadIdx.x] = S[(k0 + i) * (long)N + n0 + threadIdx.x];
  __syncthreads();
  for (int i = threadIdx.y; i < 32; i += 8) {
    long o = lz * dstZ + (n0 + i) * (long)K + k0 + threadIdx.x;
    float val = t[threadIdx.x][i];
    if (OUT_BF) ((unsigned short*)dst)[o] = f2bf(val);
    else ((float*)dst)[o] = val;
  }
}

// ------------------------------------------------- W_eff: WeT[o, p*256+c] + fused stem bias
__global__ __launch_bounds__(256)
void weff_kernel(const float* __restrict__ embWT, const float* __restrict__ convW,
                 const float* __restrict__ emb_b, const float* __restrict__ conv_b,
                 unsigned short* __restrict__ WeT, float* __restrict__ bias2) {
  __shared__ float sc[8192];
  const int o = blockIdx.x;
  const float* C = convW + (long)o * 8192;
  for (int i = threadIdx.x; i < 8192; i += 256) sc[i] = C[i];
  __syncthreads();
  const int c = threadIdx.x;
  float acc[16];
#pragma unroll
  for (int p = 0; p < 16; ++p) acc[p] = 0.f;
  for (int d = 0; d < 512; ++d) {
    float ev = embWT[d * 256 + c];
#pragma unroll
    for (int p = 0; p < 16; ++p) acc[p] += ev * sc[d * 16 + p];
  }
#pragma unroll
  for (int p = 0; p < 16; ++p) WeT[(long)o * 4096 + p * 256 + c] = f2bf(acc[p]);
  float lb = 0.f;
  for (int d = c; d < 512; d += 256) {
    float s16 = 0.f;
#pragma unroll
    for (int p = 0; p < 16; ++p) s16 += sc[d * 16 + p];
    lb += emb_b[d] * s16;
  }
#pragma unroll
  for (int of = 1; of < 64; of <<= 1) lb += __shfl_xor(lb, of, 64);
  __shared__ float red[4];
  if ((threadIdx.x & 63) == 0) red[threadIdx.x >> 6] = lb;
  __syncthreads();
  if (threadIdx.x == 0) bias2[o] = red[0] + red[1] + red[2] + red[3] + conv_b[o];
}

// ------------------------------------------------- misc small kernels
__global__ void f32_to_bf16_k(const float* __restrict__ in, unsigned short* __restrict__ out, long n4) {
  long i = (long)blockIdx.x * blockDim.x + threadIdx.x;
  const long stride = (long)gridDim.x * blockDim.x;
  for (; i < n4; i += stride) {
    float4 v = ((const float4*)in)[i];
    ushort4 o; o.x = f2bf(v.x); o.y = f2bf(v.y); o.z = f2bf(v.z); o.w = f2bf(v.w);
    ((ushort4*)out)[i] = o;
  }
}

__global__ void rotary_k(float* __restrict__ cosT, float* __restrict__ sinT) {
  int idx = blockIdx.x * 256 + threadIdx.x;
  if (idx >= SEQ * 32) return;
  int s = idx >> 5, j = idx & 31;
  float inv = expf(-(float)(2 * j) * (1.f / 64.f) * 9.210340371976184f);
  float a = (float)s * inv;
  cosT[idx] = cosf(a);
  sinT[idx] = sinf(a);
}

__global__ void concat_bias_k(const float* __restrict__ bq, const float* __restrict__ bk,
                              const float* __restrict__ bv, float* __restrict__ bqkv) {
  int idx = blockIdx.x * 256 + threadIdx.x;
  if (idx >= NLYR * QKVD) return;
  int i = idx / QKVD, j = idx % QKVD;
  float v;
  if (j < 512) v = bq[i * 512 + j];
  else if (j < 1024) v = bk[i * 512 + j - 512];
  else v = bv[i * 512 + j - 1024];
  bqkv[idx] = v;
}

__global__ __launch_bounds__(256)
void masklen_k(const float* __restrict__ mask, float* __restrict__ mlen) {
  int n = blockIdx.x;
  float s = 0.f;
  for (int i = threadIdx.x; i < 4096; i += 256) s += mask[(long)n * 4096 + i];
#pragma unroll
  for (int of = 1; of < 64; of <<= 1) s += __shfl_xor(s, of, 64);
  __shared__ float red[4];
  if ((threadIdx.x & 63) == 0) red[threadIdx.x >> 6] = s;
  __syncthreads();
  if (threadIdx.x == 0) mlen[n] = ceilf((1.f + red[0] + red[1] + red[2] + red[3]) * (1.f / 16.f));
}

__global__ void assemble_x(const float* __restrict__ stem, const float* __restrict__ bias2,
                           const float* __restrict__ posemb, const float* __restrict__ cls,
                           float* __restrict__ Xf, unsigned short* __restrict__ Xbf) {
  long idx = (long)blockIdx.x * 256 + threadIdx.x;
  if (idx >= (long)MROWS * 128) return;
  long row = idx >> 7;
  int c4 = (int)(idx & 127) * 4;
  int n = (int)(row / SEQ), s = (int)(row % SEQ);
  float4 p = *(const float4*)(posemb + (long)s * DIMD + c4);
  float4 v;
  if (s == 0) {
    float4 cv = *(const float4*)(cls + c4);
    v.x = cv.x + p.x; v.y = cv.y + p.y; v.z = cv.z + p.z; v.w = cv.w + p.w;
  } else {
    float4 st = *(const float4*)(stem + ((long)(n * 256 + s - 1)) * DIMD + c4);
    float4 b2 = *(const float4*)(bias2 + c4);
    v.x = st.x + b2.x + p.x; v.y = st.y + b2.y + p.y; v.z = st.z + b2.z + p.z; v.w = st.w + b2.w + p.w;
  }
  *(float4*)(Xf + row * DIMD + c4) = v;
  ushort4 o; o.x = f2bf(v.x); o.y = f2bf(v.y); o.z = f2bf(v.z); o.w = f2bf(v.w);
  *(ushort4*)(Xbf + row * DIMD + c4) = o;
}

// rotary + elu(+1) on fused qkv buffer (q at +0, k at +512), in place. grid MROWS, block 256.
__global__ __launch_bounds__(256)
void rot_elu_k(float* __restrict__ QKV,
               const float* __restrict__ cosT, const float* __restrict__ sinT,
               const float* __restrict__ mlen) {
  int row = blockIdx.x;
  int n = row / SEQ, s = row % SEQ;
  int t = threadIdx.x, h = t >> 5, j = t & 31;
  long base = (long)row * QKVD + h * 64 + j;
  float c = cosT[s * 32 + j], si = sinT[s * 32 + j];
  float q0 = QKV[base], q1 = QKV[base + 32];
  QKV[base] = elu1(q0 * c - q1 * si);
  QKV[base + 32] = elu1(q1 * c + q0 * si);
  float km = ((float)s < mlen[n]) ? 1.f : 0.f;
  float k0 = QKV[base + 512], k1 = QKV[base + 544];
  QKV[base + 512] = elu1(k0 * c - k1 * si) * km;
  QKV[base + 544] = elu1(k1 * c + k0 * si) * km;
}

// KV[n,h,d,m] = sum_s K[n,s,h,d]*V[n,s,h,m]; Ksum[n,h,d]. grid 256 (n*8+h), block 256.
// 256 threads (NOT 512): keeps the VGPR cap at 256 so acc[16]+temps never spill
// (round-3's 512-thread variant hit the 128-VGPR cap and generated 1.6 GB of
// scratch traffic per dispatch).
__global__ __launch_bounds__(256)
void kv_kernel(const float* __restrict__ QKV, float* __restrict__ KV, float* __restrict__ Ksum) {
  int n = blockIdx.x >> 3, h = blockIdx.x & 7;
  __shared__ float sK[64][64];
  __shared__ float sV[64][64];
  int t = threadIdx.x;
  int d = t & 63, mg = t >> 6;   // mg in 0..3
  float acc[16];
#pragma unroll
  for (int i = 0; i < 16; ++i) acc[i] = 0.f;
  float ks = 0.f;
  for (int s0 = 0; s0 < 320; s0 += 64) {
#pragma unroll
    for (int kk = 0; kk < 4; ++kk) {
      int idx = kk * 256 + t;
      int r = idx >> 4, c4 = (idx & 15) * 4;
      int srow = s0 + r;
      float4 kv = {0, 0, 0, 0}, vv = {0, 0, 0, 0};
      if (srow < SEQ) {
        long goff = ((long)(n * SEQ + srow)) * QKVD + h * 64 + c4;
        kv = *(const float4*)(QKV + goff + 512);
        vv = *(const float4*)(QKV + goff + 1024);
      }
      *(float4*)&sK[r][c4] = kv;
      *(float4*)&sV[r][c4] = vv;
    }
    __syncthreads();
    for (int s = 0; s < 64; ++s) {
      float kd = sK[s][d];
      if (mg == 0) ks += kd;
      float4 v0 = *(const float4*)&sV[s][mg * 16];
      float4 v1 = *(const float4*)&sV[s][mg * 16 + 4];
      float4 v2 = *(const float4*)&sV[s][mg * 16 + 8];
      float4 v3 = *(const float4*)&sV[s][mg * 16 + 12];
      acc[0] += kd * v0.x; acc[1] += kd * v0.y; acc[2] += kd * v0.z; acc[3] += kd * v0.w;
      acc[4] += kd * v1.x; acc[5] += kd * v1.y; acc[6] += kd * v1.z; acc[7] += kd * v1.w;
      acc[8] += kd * v2.x; acc[9] += kd * v2.y; acc[10] += kd * v2.z; acc[11] += kd * v2.w;
      acc[12] += kd * v3.x; acc[13] += kd * v3.y; acc[14] += kd * v3.z; acc[15] += kd * v3.w;
    }
    __syncthreads();
  }
  float* out = KV + ((long)(n * 8 + h)) * 4096 + d * 64 + mg * 16;
#pragma unroll
  for (int i = 0; i < 16; ++i) out[i] = acc[i];
  if (mg == 0) Ksum[(n * 8 + h) * 64 + d] = ks;
}

// attention out (bf16). grid (32, 65), block 512: thread=(h,m); 4 query rows per block.
__global__ __launch_bounds__(512)
void attn_out_k(const float* __restrict__ QKV, const float* __restrict__ KV,
                const float* __restrict__ Ksum, unsigned short* __restrict__ Obf) {
  int n = blockIdx.x, lg = blockIdx.y;
  int t = threadIdx.x, h = t >> 6, m = t & 63;
  __shared__ float sQ[4][512];
#pragma unroll
  for (int r = 0; r < 4; ++r) {
    int lq = lg * 4 + r;
    sQ[r][t] = (lq < SEQ) ? QKV[((long)(n * SEQ + lq)) * QKVD + t] : 0.f;
  }
  __syncthreads();
  float ksd = Ksum[(n * 8 + h) * 64 + m];
  float Zv[4];
#pragma unroll
  for (int r = 0; r < 4; ++r) {
    float z = sQ[r][h * 64 + m] * ksd;
#pragma unroll
    for (int of = 1; of < 64; of <<= 1) z += __shfl_xor(z, of, 64);
    Zv[r] = 1.f / (z + 1e-6f);
  }
  const float* kvp = KV + ((long)(n * 8 + h)) * 4096 + m;
  float acc[4] = {0.f, 0.f, 0.f, 0.f};
  for (int d = 0; d < 64; ++d) {
    float kvv = kvp[d * 64];
#pragma unroll
    for (int r = 0; r < 4; ++r) acc[r] += sQ[r][h * 64 + d] * kvv;
  }
#pragma unroll
  for (int r = 0; r < 4; ++r) {
    int lq = lg * 4 + r;
    if (lq < SEQ) Obf[((long)(n * SEQ + lq)) * DIMD + t] = f2bf(acc[r] * Zv[r]);
  }
}

// y = LN(x + a) -> fp32 + bf16. grid MROWS, block 128.
__global__ __launch_bounds__(128)
void add_ln_k(const float* __restrict__ X, const float* __restrict__ A,
              const float* __restrict__ g, const float* __restrict__ b,
              float* __restrict__ Yf, unsigned short* __restrict__ Ybf) {
  int row = blockIdx.x, t = threadIdx.x;
  long base = (long)row * DIMD + t * 4;
  float4 xv = *(const float4*)(X + base);
  float4 av = *(const float4*)(A + base);
  float4 s;
  s.x = xv.x + av.x; s.y = xv.y + av.y; s.z = xv.z + av.z; s.w = xv.w + av.w;
  float sum = s.x + s.y + s.z + s.w;
  float sq = s.x * s.x + s.y * s.y + s.z * s.z + s.w * s.w;
#pragma unroll
  for (int of = 1; of < 64; of <<= 1) { sum += __shfl_xor(sum, of, 64); sq += __shfl_xor(sq, of, 64); }
  __shared__ float red[4];
  if ((t & 63) == 0) { red[(t >> 6) * 2] = sum; red[(t >> 6) * 2 + 1] = sq; }
  __syncthreads();
  sum = red[0] + red[2]; sq = red[1] + red[3];
  float mean = sum * (1.f / 512.f);
  float var = sq * (1.f / 512.f) - mean * mean;
  float rstd = rsqrtf(var + 1e-5f);
  float4 gv = *(const float4*)(g + t * 4);
  float4 bv = *(const float4*)(b + t * 4);
  float4 y;
  y.x = (s.x - mean) * rstd * gv.x + bv.x;
  y.y = (s.y - mean) * rstd * gv.y + bv.y;
  y.z = (s.z - mean) * rstd * gv.z + bv.z;
  y.w = (s.w - mean) * rstd * gv.w + bv.w;
  *(float4*)(Yf + base) = y;
  ushort4 o; o.x = f2bf(y.x); o.y = f2bf(y.y); o.z = f2bf(y.z); o.w = f2bf(y.w);
  *(ushort4*)(Ybf + base) = o;
}

// final LN + output heads. grid MROWS, block 128. out fp32: [32 global][8192 local]
__global__ __launch_bounds__(128)
void final_head_k(const float* __restrict__ X, const float* __restrict__ g, const float* __restrict__ b,
                  const float* __restrict__ condemb, const int* __restrict__ cond,
                  const float* __restrict__ outgW, const float* __restrict__ outgb,
                  const float* __restrict__ outlW, const float* __restrict__ outlb,
                  float* __restrict__ out) {
  int row = blockIdx.x, t = threadIdx.x;
  int n = row / SEQ, s = row % SEQ;
  long base = (long)row * DIMD + t * 4;
  float4 xv = *(const float4*)(X + base);
  float sum = xv.x + xv.y + xv.z + xv.w;
  float sq = xv.x * xv.x + xv.y * xv.y + xv.z * xv.z + xv.w * xv.w;
#pragma unroll
  for (int of = 1; of < 64; of <<= 1) { sum += __shfl_xor(sum, of, 64); sq += __shfl_xor(sq, of, 64); }
  __shared__ float red[4];
  if ((t & 63) == 0) { red[(t >> 6) * 2] = sum; red[(t >> 6) * 2 + 1] = sq; }
  __syncthreads();
  sum = red[0] + red[2]; sq = red[1] + red[3];
  float mean = sum * (1.f / 512.f);
  float var = sq * (1.f / 512.f) - mean * mean;
  float rstd = rsqrtf(var + 1e-5f);
  float4 gv = *(const float4*)(g + t * 4);
  float4 bv = *(const float4*)(b + t * 4);
  const float* wsel = (s == 0) ? outgW : outlW;
  const float* ce = condemb + (long)cond[n] * DIMD;
  float4 wv = *(const float4*)(wsel + t * 4);
  float4 cv = *(const float4*)(ce + t * 4);
  float l0 = (xv.x - mean) * rstd * gv.x + bv.x;
  float l1 = (xv.y - mean) * rstd * gv.y + bv.y;
  float l2 = (xv.z - mean) * rstd * gv.z + bv.z;
  float l3 = (xv.w - mean) * rstd * gv.w + bv.w;
  float pl = l0 * wv.x + l1 * wv.y + l2 * wv.z + l3 * wv.w;
  float pc = l0 * cv.x + l1 * cv.y + l2 * cv.z + l3 * cv.w;
#pragma unroll
  for (int of = 1; of < 64; of <<= 1) { pl += __shfl_xor(pl, of, 64); pc += __shfl_xor(pc, of, 64); }
  __shared__ float red2[4];
  if ((t & 63) == 0) { red2[(t >> 6) * 2] = pl; red2[(t >> 6) * 2 + 1] = pc; }
  __syncthreads();
  if (t == 0) {
    float res = red2[0] + red2[2] + red2[1] + red2[3] + ((s == 0) ? outgb[0] : outlb[0]);
    long oi = (s == 0) ? (long)n : (32 + (long)n * 256 + (s - 1));
    out[oi] = res;
  }
}

// ---------------------------------------------------------------- host
extern "C" void kernel_launch(void* const* d_in, const int* in_sizes, int n_in,
                              void* d_out, int out_size, void* d_ws, size_t ws_size,
                              hipStream_t stream) {
  const float* inputs    = (const float*)d_in[0];
  const float* input_mask= (const float*)d_in[1];
  const int*   cond      = (const int*)d_in[2];
  const float* emb_W     = (const float*)d_in[3];
  const float* emb_b     = (const float*)d_in[4];
  const float* conv_W    = (const float*)d_in[5];
  const float* conv_b    = (const float*)d_in[6];
  const float* pos_emb   = (const float*)d_in[7];
  const float* cls_token = (const float*)d_in[8];
  const float* Wq = (const float*)d_in[9];   const float* bq = (const float*)d_in[10];
  const float* Wk = (const float*)d_in[11];  const float* bk = (const float*)d_in[12];
  const float* Wv = (const float*)d_in[13];  const float* bv = (const float*)d_in[14];
  const float* Wo = (const float*)d_in[15];  const float* bo = (const float*)d_in[16];
  const float* ln1_g = (const float*)d_in[17]; const float* ln1_b = (const float*)d_in[18];
  const float* W1 = (const float*)d_in[19];  const float* b1 = (const float*)d_in[20];
  const float* W2 = (const float*)d_in[21];  const float* b2 = (const float*)d_in[22];
  const float* ln2_g = (const float*)d_in[23]; const float* ln2_b = (const float*)d_in[24];
  const float* normf_g = (const float*)d_in[25]; const float* normf_b = (const float*)d_in[26];
  const float* cond_emb = (const float*)d_in[27];
  const float* outg_W = (const float*)d_in[28]; const float* outg_b = (const float*)d_in[29];
  const float* outl_W = (const float*)d_in[30]; const float* outl_b = (const float*)d_in[31];

  char* ws = (char*)d_ws;
  size_t off = 0;
  auto alloc = [&](size_t bytes) -> char* {
    char* p = ws + off;
    off += (bytes + 255) & ~(size_t)255;
    return p;
  };
  unsigned short* WeT   = (unsigned short*)alloc((size_t)512 * 4096 * 2);
  float*          embWT = (float*)alloc((size_t)512 * 256 * 4);
  float*          bias2 = (float*)alloc(512 * 4);
  float*          cosT  = (float*)alloc(SEQ * 32 * 4);
  float*          sinT  = (float*)alloc(SEQ * 32 * 4);
  float*          mlen  = (float*)alloc(32 * 4);
  unsigned short* Wqkv  = (unsigned short*)alloc((size_t)NLYR * QKVD * 512 * 2);
  float*          bqkv  = (float*)alloc((size_t)NLYR * QKVD * 4);
  unsigned short* WoT = (unsigned short*)alloc((size_t)NLYR * 512 * 512 * 2);
  unsigned short* W1T = (unsigned short*)alloc((size_t)NLYR * 2048 * 512 * 2);
  unsigned short* W2T = (unsigned short*)alloc((size_t)NLYR * 512 * 2048 * 2);
  // in_bf (64 MB) only needed before the stem GEMM; tqkv (51 MB) aliases it.
  char*           big  = alloc((size_t)MSTEM * KSTEM * 2);
  unsigned short* in_bf = (unsigned short*)big;
  float*          tqkv  = (float*)big;
  float*          x_f  = (float*)alloc((size_t)MPAD * DIMD * 4);
  unsigned short* x_bf = (unsigned short*)alloc((size_t)MPAD * DIMD * 2);
  float*          y_f  = (float*)alloc((size_t)MPAD * DIMD * 4);
  unsigned short* y_bf = (unsigned short*)alloc((size_t)MPAD * DIMD * 2);
  float*          t0   = (float*)alloc((size_t)MPAD * DIMD * 4);
  unsigned short* attn_bf = (unsigned short*)alloc((size_t)MPAD * DIMD * 2);
  unsigned short* h_bf = (unsigned short*)alloc((size_t)MPAD * FFD * 2);
  float*          KV   = (float*)alloc((size_t)32 * 8 * 64 * 64 * 4);
  float*          Ksum = (float*)alloc((size_t)32 * 8 * 64 * 4);
  (void)ws_size; (void)in_sizes; (void)n_in; (void)out_size;

  dim3 tb(32, 8);
  // fused QKV weight: per layer rows [0..512)=Wq^T, [512..1024)=Wk^T, [1024..1536)=Wv^T
  transpose_k<1><<<dim3(16, 16, 8), tb, 0, stream>>>(Wq, Wqkv, 512, 512, (long)QKVD * 512);
  transpose_k<1><<<dim3(16, 16, 8), tb, 0, stream>>>(Wk, Wqkv + (size_t)512 * 512, 512, 512, (long)QKVD * 512);
  transpose_k<1><<<dim3(16, 16, 8), tb, 0, stream>>>(Wv, Wqkv + (size_t)1024 * 512, 512, 512, (long)QKVD * 512);
  transpose_k<1><<<dim3(16, 16, 8), tb, 0, stream>>>(Wo, WoT, 512, 512, (long)512 * 512);
  transpose_k<1><<<dim3(16, 64, 8), tb, 0, stream>>>(W1, W1T, 512, 2048, (long)512 * 2048);
  transpose_k<1><<<dim3(64, 16, 8), tb, 0, stream>>>(W2, W2T, 2048, 512, (long)2048 * 512);
  transpose_k<0><<<dim3(8, 16, 1), tb, 0, stream>>>(emb_W, embWT, 256, 512, 0);
  concat_bias_k<<<(NLYR * QKVD + 255) / 256, 256, 0, stream>>>(bq, bk, bv, bqkv);
  weff_kernel<<<512, 256, 0, stream>>>(embWT, conv_W, emb_b, conv_b, WeT, bias2);
  f32_to_bf16_k<<<4096, 256, 0, stream>>>(inputs, in_bf, (long)MSTEM * KSTEM / 4);
  rotary_k<<<(SEQ * 32 + 255) / 256, 256, 0, stream>>>(cosT, sinT);
  masklen_k<<<32, 256, 0, stream>>>(input_mask, mlen);

  // stem GEMM: (8192 x 4096) @ (4096 x 512) -> t0   [CFG1: BN=64, grid 512]
  gemm_bt<1, 0><<<dim3(MSTEM / 128, 8), 256, 0, stream>>>(in_bf, WeT, nullptr, t0, KSTEM, DIMD);
  assemble_x<<<(MROWS * 128 + 255) / 256, 256, 0, stream>>>(t0, bias2, pos_emb, cls_token, x_f, x_bf);

  for (int i = 0; i < NLYR; ++i) {
    const unsigned short* wqkv = Wqkv + (size_t)i * QKVD * 512;
    const unsigned short* wo = WoT + (size_t)i * 512 * 512;
    const unsigned short* w1 = W1T + (size_t)i * 2048 * 512;
    const unsigned short* w2 = W2T + (size_t)i * 512 * 2048;
    // fused QKV: (8320 x 512) @ (512 x 1536) -> tqkv  [CFG0, grid 780]
    gemm_bt<0, 0><<<dim3(MPAD / 128, QKVD / 128), 256, 0, stream>>>(x_bf, wqkv, bqkv + i * QKVD, tqkv, 512, QKVD);
    rot_elu_k<<<MROWS, 256, 0, stream>>>(tqkv, cosT, sinT, mlen);
    kv_kernel<<<256, 256, 0, stream>>>(tqkv, KV, Ksum);
    attn_out_k<<<dim3(32, 65), 512, 0, stream>>>(tqkv, KV, Ksum, attn_bf);
    // O-proj [CFG1, grid 520]
    gemm_bt<1, 0><<<dim3(MPAD / 128, 8), 256, 0, stream>>>(attn_bf, wo, bo + i * 512, t0, 512, 512);
    add_ln_k<<<MROWS, 128, 0, stream>>>(x_f, t0, ln1_g + i * 512, ln1_b + i * 512, y_f, y_bf);
    // FF1 [CFG0, grid 1040]
    gemm_bt<0, 1><<<dim3(MPAD / 128, 16), 256, 0, stream>>>(y_bf, w1, b1 + i * 2048, h_bf, 512, 2048);
    // FF2 [CFG1, grid 520]
    gemm_bt<1, 0><<<dim3(MPAD / 128, 8), 256, 0, stream>>>(h_bf, w2, b2 + i * 512, t0, 2048, 512);
    add_ln_k<<<MROWS, 128, 0, stream>>>(y_f, t0, ln2_g + i * 512, ln2_b + i * 512, x_f, x_bf);
  }
  final_head_k<<<MROWS, 128, 0, stream>>>(x_f, normf_g, normf_b, cond_emb, cond,
                                          outg_W, outg_b, outl_W, outl_b, (float*)d_out);
}